// Round 15
// baseline (143.513 us; speedup 1.0000x reference)
//
#include <hip/hip_runtime.h>

#define NN 100000
#define NE 1600000
#define F  128

// radix partition params
#define SH   8                  // bucket = dst >> 8
#define NPB  256                // nodes per bucket
#define NBKT 391                // ceil(NN/256)
#define B1   256                // pass-1 blocks
#define CH1  6250               // NE / B1 exactly
#define MATN (NBKT * B1)        // 100096
#define MATP (98 * 1024)        // padded to scan grid (100352)
#define BCAP2 6144              // fill2 LDS stage cap (mean 4096, +32 sigma)

#define SB   256                // stats blocks (partials, no atomics)

constexpr float EPS   = 1e-5f;
constexpr float SLOPE = 0.01f;

typedef __attribute__((ext_vector_type(8))) short short8;
typedef __attribute__((ext_vector_type(4))) float f32x4;
typedef __attribute__((ext_vector_type(2))) float f32x2;

__device__ inline unsigned int bf16rne(float f) {
    unsigned int u = __float_as_uint(f);
    return (u + 0x7fffu + ((u >> 16) & 1u)) >> 16;
}
__device__ inline unsigned int pack2(float a, float b) {
    return bf16rne(a) | (bf16rne(b) << 16);
}
__device__ inline f32x2 pkadd(f32x2 a, f32x2 b) {
    f32x2 d;
    asm("v_pk_add_f32 %0, %1, %2" : "=v"(d) : "v"(a), "v"(b));
    return d;
}
__device__ inline f32x2 pkfma(f32x2 a, f32x2 b, f32x2 c) {
    f32x2 d;
    asm("v_pk_fma_f32 %0, %1, %2, %3" : "=v"(d) : "v"(a), "v"(b), "v"(c));
    return d;
}
// fp8 e4m3 HW converters (gfx950 OCP fp8)
__device__ inline f32x2 fp8lo(unsigned int u) {
    return __builtin_amdgcn_cvt_pk_f32_fp8(u, false);   // bytes 0,1 -> 2 floats
}
__device__ inline f32x2 fp8hi(unsigned int u) {
    return __builtin_amdgcn_cvt_pk_f32_fp8(u, true);    // bytes 2,3 -> 2 floats
}
__device__ inline unsigned int fp8pack4(float a, float b, float c, float d) {
    int o = 0;
    o = __builtin_amdgcn_cvt_pk_fp8_f32(a, b, o, false);
    o = __builtin_amdgcn_cvt_pk_fp8_f32(c, d, o, true);
    return (unsigned int)o;
}

// ---------------- pass 1a: per-block bucket histogram (dual, wave-parity) + W prep ----------------
__global__ __launch_bounds__(1024) void k_hist1(const int* __restrict__ dst,
                                                unsigned int* __restrict__ mat,
                                                const float* __restrict__ Wm,
                                                unsigned int* __restrict__ Wt,
                                                unsigned int* __restrict__ done) {
    __shared__ unsigned int h[2][NBKT];
    const int t = threadIdx.x;
    if (t < NBKT) { h[0][t] = 0u; h[1][t] = 0u; }
    __syncthreads();
    if (blockIdx.x < 8) {                        // fused W prep (8192 entries)
        int idx = blockIdx.x * 1024 + t;
        int p = idx & 3, lane = (idx >> 2) & 63, n = (idx >> 8) & 7, kk = idx >> 11;
        int k0 = kk * 32 + (lane >> 4) * 8 + 2 * p;
        int c  = n * 16 + (lane & 15);
        unsigned int lo = bf16rne(Wm[k0 * F + c]);
        unsigned int hi = bf16rne(Wm[(k0 + 1) * F + c]);
        Wt[idx] = lo | (hi << 16);
    }
    if (blockIdx.x == 8 && t == 0) done[0] = 0u;  // reset stats ticket each launch
    const int par = (t >> 6) & 1;                 // wave parity
    const int e0 = blockIdx.x * CH1;
    for (int i = t; i < CH1; i += 1024)
        atomicAdd(&h[par][dst[e0 + i] >> SH], 1u);
    __syncthreads();
    if (t < NBKT) mat[t * B1 + blockIdx.x] = h[0][t] + h[1][t];
}

// ---------------- scanA: inclusive per 1024-block + block sums ----------------
__global__ __launch_bounds__(1024) void k_scanA(const unsigned int* __restrict__ mat,
                                                unsigned int* __restrict__ scn,
                                                unsigned int* __restrict__ bsums) {
    __shared__ unsigned int ps[1024];
    const int t = threadIdx.x;
    const int i = blockIdx.x * 1024 + t;        // grid 98*1024 == MATP
    unsigned int v = mat[i];                     // pad region: garbage, harmless
    ps[t] = v;
    __syncthreads();
    for (int off = 1; off < 1024; off <<= 1) {
        unsigned int a = (t >= off) ? ps[t - off] : 0u;
        __syncthreads();
        ps[t] += a;
        __syncthreads();
    }
    scn[i] = ps[t];                              // inclusive within block
    if (t == 1023) bsums[blockIdx.x] = ps[1023];
}

// exclusive(i) = scn[i] + boff[i>>10] - mat[i]; boff computed in-block from bsums

// ---------------- pass 1c: scatter edges into bucket segments ----------------
__global__ __launch_bounds__(1024) void k_scat1(const int* __restrict__ ei,
                                                const unsigned int* __restrict__ mat,
                                                const unsigned int* __restrict__ scn,
                                                const unsigned int* __restrict__ bsums,
                                                unsigned int* __restrict__ ebuf) {
    __shared__ unsigned int cur[NBKT];
    __shared__ unsigned int bo[128];
    const int t = threadIdx.x;
    if (t < 128) {                               // 98-entry exclusive scan of bsums
        unsigned int v = (t < 98) ? bsums[t] : 0u;
        bo[t] = v;
        for (int off = 1; off < 128; off <<= 1) {
            __syncthreads();
            unsigned int a = (t >= off) ? bo[t - off] : 0u;
            __syncthreads();
            bo[t] += a;
        }
        bo[t] -= v;                              // exclusive
    } else {
        for (int off = 1; off < 128; off <<= 1) { __syncthreads(); __syncthreads(); }
    }
    __syncthreads();
    if (t < NBKT) {
        int idx = t * B1 + blockIdx.x;
        cur[t] = scn[idx] + bo[idx >> 10] - mat[idx];
    }
    __syncthreads();
    const int e0 = blockIdx.x * CH1;
    for (int i = t; i < CH1; i += 1024) {
        int s = ei[e0 + i];
        int d = ei[NE + e0 + i];
        unsigned int pos = atomicAdd(&cur[d >> SH], 1u);
        ebuf[pos] = ((unsigned int)(d & (NPB - 1)) << 17) | (unsigned int)s;
    }
}

// ---------------- pass 2: LDS-staged per-bucket degree/scan/row_start/dis + csr ----------------
__global__ __launch_bounds__(256) void k_fill2(const unsigned int* __restrict__ mat,
                                               const unsigned int* __restrict__ scn,
                                               const unsigned int* __restrict__ bsums,
                                               const unsigned int* __restrict__ ebuf,
                                               int* __restrict__ row_start,
                                               float* __restrict__ dis,
                                               int* __restrict__ csr) {
    __shared__ unsigned int stage[BCAP2];
    __shared__ unsigned int hist[NPB];
    __shared__ unsigned int cur[NPB];
    __shared__ unsigned int ps[NPB];
    __shared__ unsigned int bo[128];
    const int t = threadIdx.x;
    const int bkt = blockIdx.x;
    hist[t] = 0u;
    if (t < 128) {                               // 98-entry exclusive scan of bsums
        unsigned int v = (t < 98) ? bsums[t] : 0u;
        bo[t] = v;
        for (int off = 1; off < 128; off <<= 1) {
            __syncthreads();
            unsigned int a = (t >= off) ? bo[t - off] : 0u;
            __syncthreads();
            bo[t] += a;
        }
        bo[t] -= v;
    } else {
        for (int off = 1; off < 128; off <<= 1) { __syncthreads(); __syncthreads(); }
    }
    __syncthreads();
    const int i0 = bkt * B1;
    const unsigned int ebase = scn[i0] + bo[i0 >> 10] - mat[i0];
    unsigned int eend;
    if (bkt == NBKT - 1) eend = (unsigned int)NE;
    else {
        const int i1 = (bkt + 1) * B1;
        eend = scn[i1] + bo[i1 >> 10] - mat[i1];
    }
    const unsigned int n = eend - ebase;
    const unsigned int m = (n < BCAP2) ? n : BCAP2;
    for (unsigned int i = t; i < m; i += 256) {
        unsigned int v = ebuf[ebase + i];
        stage[i] = v;
        atomicAdd(&hist[v >> 17], 1u);
    }
    for (unsigned int i = BCAP2 + t; i < n; i += 256)   // overflow path (≈never)
        atomicAdd(&hist[ebuf[ebase + i] >> 17], 1u);
    __syncthreads();
    const unsigned int deg = hist[t];
    ps[t] = deg;
    __syncthreads();
    for (int off = 1; off < 256; off <<= 1) {
        unsigned int a = (t >= off) ? ps[t - off] : 0u;
        __syncthreads();
        ps[t] += a;
        __syncthreads();
    }
    const unsigned int ex = (t == 0) ? 0u : ps[t - 1];
    cur[t] = ebase + ex;
    const int node = bkt * NPB + t;
    if (node <= NN) row_start[node] = (int)(ebase + ex);   // node==NN lands on NE
    if (node < NN)  dis[node] = rsqrtf((float)(deg + 1u));
    __syncthreads();
    for (unsigned int i = t; i < m; i += 256) {
        unsigned int v = stage[i];
        unsigned int pos = atomicAdd(&cur[v >> 17], 1u);
        csr[pos] = (int)(v & 0x1FFFFu);
    }
    for (unsigned int i = BCAP2 + t; i < n; i += 256) {   // overflow path
        unsigned int v = ebuf[ebase + i];
        unsigned int pos = atomicAdd(&cur[v >> 17], 1u);
        csr[pos] = (int)(v & 0x1FFFFu);
    }
}

// ---------------- MFMA GEMM: g = fp8(x @ W * dis)  (swapped operands) ----------------
__global__ __launch_bounds__(256) void k_gemm(const float* __restrict__ x,
                                              const unsigned int* __restrict__ Wt,
                                              const float* __restrict__ dis,
                                              unsigned int* __restrict__ g32) {
    __shared__ unsigned int xl[128 * 64];   // 32 KB bf16-pair tile
    const int tid = threadIdx.x;
    const int lane = tid & 63, wave = tid >> 6;
    const int row0 = blockIdx.x * 128;

#pragma unroll
    for (int i = 0; i < 16; ++i) {
        int fi = i * 256 + tid;            // 0..4095
        int lr = fi >> 5;                  // local row (32 thr/row)
        int cf = (fi & 31) * 4;            // f32 col
        int gr = row0 + lr; if (gr >= NN) gr = NN - 1;
        float4 v = *(const float4*)(x + (size_t)gr * F + cf);
        unsigned int u0 = pack2(v.x, v.y);
        unsigned int u1 = pack2(v.z, v.w);
        int cu = (cf >> 1) ^ ((lr & 7) << 2);
        uint2 w2; w2.x = u0; w2.y = u1;
        *(uint2*)&xl[lr * 64 + cu] = w2;
    }
    __syncthreads();

    const int rbase = row0 + wave * 32;
    short8 afr[2][4];                       // x fragments (B operand)
#pragma unroll
    for (int m = 0; m < 2; ++m) {
        int lr = wave * 32 + m * 16 + (lane & 15);
#pragma unroll
        for (int kk = 0; kk < 4; ++kk) {
            int cu = (kk * 16 + (lane >> 4) * 4) ^ ((lr & 7) << 2);
            afr[m][kk] = *(const short8*)&xl[lr * 64 + cu];
        }
    }

    f32x4 acc[2][8];
#pragma unroll
    for (int m = 0; m < 2; ++m)
#pragma unroll
        for (int n = 0; n < 8; ++n) { f32x4 z = {0.f, 0.f, 0.f, 0.f}; acc[m][n] = z; }

    const uint4* Wt4 = (const uint4*)Wt;
#pragma unroll
    for (int kk = 0; kk < 4; ++kk) {
        union { uint4 u; short8 s; } bfr[8];   // W^T fragments (A operand)
#pragma unroll
        for (int n = 0; n < 8; ++n) bfr[n].u = Wt4[(kk * 8 + n) * 64 + lane];
#pragma unroll
        for (int m = 0; m < 2; ++m)
#pragma unroll
            for (int n = 0; n < 8; ++n)
                acc[m][n] = __builtin_amdgcn_mfma_f32_16x16x32_bf16(bfr[n].s, afr[m][kk], acc[m][n], 0, 0, 0);
    }

    // epilogue: lane owns xrow = rbase + m*16 + (lane&15), wcols n*16+(lane>>4)*4 .. +3
#pragma unroll
    for (int m = 0; m < 2; ++m) {
        int xr = rbase + m * 16 + (lane & 15);
        bool ok = xr < NN;
        float d = ok ? dis[xr] : 0.0f;
        unsigned int* gp = g32 + (size_t)(ok ? xr : 0) * 32 + (lane >> 4);
#pragma unroll
        for (int n = 0; n < 8; ++n) {
            unsigned int w = fp8pack4(acc[m][n][0] * d, acc[m][n][1] * d,
                                      acc[m][n][2] * d, acc[m][n][3] * d);
            if (ok) gp[n * 4] = w;
        }
    }
}

// ---------------- gather: agg8 = fp8(b + dis[n]*sum(g[src] over src ∪ {n})) ----------------
// 512 threads = 8 nodes/block; wave per node; fp8 rows (128B = 2 lines);
// 16 lanes/row (uint2), 4 row-slots, 4 rows unrolled/iter; fp8 HW cvt + pk_add.
__global__ __launch_bounds__(512) void k_gather(const unsigned int* __restrict__ g32,
                                                const int* __restrict__ csr,
                                                const int* __restrict__ row_start,
                                                const float* __restrict__ dis,
                                                const float* __restrict__ b,
                                                unsigned int* __restrict__ agg8) {
    const int lane = threadIdx.x & 63;
    const int node = blockIdx.x * 8 + (threadIdx.x >> 6);
    if (node >= NN) return;
    const int q = lane >> 4;           // row slot (0..3)
    const int c = lane & 15;           // uint2 col: features 8c..8c+7
    const int j = row_start[node];
    const int e = row_start[node + 1];
    const int L = e - j + 1;           // + self
    int sv = (j + lane < e) ? csr[j + lane] : node;   // preload ids; self past end
    f32x2 A0 = {0.f, 0.f}, A1 = A0, A2 = A0, A3 = A0;
    int k = 0;
    const int L1 = (L < 64) ? L : 64;
    for (; k < L1; k += 16) {
        int k0 = k + q, k1 = k0 + 4, k2 = k0 + 8, k3 = k0 + 12;
        int r0 = __shfl(sv, k0);
        int r1 = __shfl(sv, k1);
        int r2 = __shfl(sv, k2);
        int r3 = __shfl(sv, k3);
        bool p0 = k0 < L, p1 = k1 < L, p2 = k2 < L, p3 = k3 < L;
        uint2 v0, v1, v2, v3;
        if (p0) v0 = *(const uint2*)&g32[(size_t)r0 * 32 + c * 2];
        if (p1) v1 = *(const uint2*)&g32[(size_t)r1 * 32 + c * 2];
        if (p2) v2 = *(const uint2*)&g32[(size_t)r2 * 32 + c * 2];
        if (p3) v3 = *(const uint2*)&g32[(size_t)r3 * 32 + c * 2];
        if (p0) {
            A0 = pkadd(A0, fp8lo(v0.x)); A1 = pkadd(A1, fp8hi(v0.x));
            A2 = pkadd(A2, fp8lo(v0.y)); A3 = pkadd(A3, fp8hi(v0.y));
        }
        if (p1) {
            A0 = pkadd(A0, fp8lo(v1.x)); A1 = pkadd(A1, fp8hi(v1.x));
            A2 = pkadd(A2, fp8lo(v1.y)); A3 = pkadd(A3, fp8hi(v1.y));
        }
        if (p2) {
            A0 = pkadd(A0, fp8lo(v2.x)); A1 = pkadd(A1, fp8hi(v2.x));
            A2 = pkadd(A2, fp8lo(v2.y)); A3 = pkadd(A3, fp8hi(v2.y));
        }
        if (p3) {
            A0 = pkadd(A0, fp8lo(v3.x)); A1 = pkadd(A1, fp8hi(v3.x));
            A2 = pkadd(A2, fp8lo(v3.y)); A3 = pkadd(A3, fp8hi(v3.y));
        }
    }
    for (; k < L; k += 16) {           // rare: deg+1 > 64
#pragma unroll
        for (int s = 0; s < 4; ++s) {
            int ks = k + q + s * 4;
            if (ks < L) {
                int rs = (j + ks < e) ? csr[j + ks] : node;
                uint2 v = *(const uint2*)&g32[(size_t)rs * 32 + c * 2];
                A0 = pkadd(A0, fp8lo(v.x)); A1 = pkadd(A1, fp8hi(v.x));
                A2 = pkadd(A2, fp8lo(v.y)); A3 = pkadd(A3, fp8hi(v.y));
            }
        }
    }
#define RED2(A) A.x += __shfl_xor(A.x, 16); A.x += __shfl_xor(A.x, 32); \
                A.y += __shfl_xor(A.y, 16); A.y += __shfl_xor(A.y, 32);
    RED2(A0) RED2(A1) RED2(A2) RED2(A3)
#undef RED2
    if (q == 0) {                      // lanes 0..15 write the row (128B contiguous)
        float d = dis[node];
        const float4* bp = (const float4*)&b[c * 8];
        float4 b0 = bp[0], b1 = bp[1];
        uint2 w;
        w.x = fp8pack4(b0.x + d * A0.x, b0.y + d * A0.y,
                       b0.z + d * A1.x, b0.w + d * A1.y);
        w.y = fp8pack4(b1.x + d * A2.x, b1.y + d * A2.y,
                       b1.z + d * A3.x, b1.w + d * A3.y);
        *(uint2*)&agg8[(size_t)node * 32 + c * 2] = w;
    }
}

// ---------------- stats: fp8 agg streaming + last-block fused reduction ----------------
__global__ __launch_bounds__(256) void k_stats(const unsigned int* __restrict__ agg8,
                                               float* __restrict__ partials,
                                               float* __restrict__ stats,
                                               unsigned int* __restrict__ done) {
    __shared__ float lds[4][8][32];
    __shared__ unsigned int isLast;
    const int tid = threadIdx.x;
    const int lane = tid & 63, wave = tid >> 6;
    const uint4* a4 = (const uint4*)agg8;
    const long total  = (long)NN * 8;
    const long stride = (long)SB * 256;
    f32x2 S[8], Q[8];
#pragma unroll
    for (int i = 0; i < 8; ++i) { f32x2 z = {0.f, 0.f}; S[i] = z; Q[i] = z; }
    for (long i = (long)blockIdx.x * 256 + tid; i < total; i += stride) {
        uint4 v = a4[i];
        f32x2 p0 = fp8lo(v.x), p1 = fp8hi(v.x), p2 = fp8lo(v.y), p3 = fp8hi(v.y);
        f32x2 p4 = fp8lo(v.z), p5 = fp8hi(v.z), p6 = fp8lo(v.w), p7 = fp8hi(v.w);
        S[0] = pkadd(S[0], p0); Q[0] = pkfma(p0, p0, Q[0]);
        S[1] = pkadd(S[1], p1); Q[1] = pkfma(p1, p1, Q[1]);
        S[2] = pkadd(S[2], p2); Q[2] = pkfma(p2, p2, Q[2]);
        S[3] = pkadd(S[3], p3); Q[3] = pkfma(p3, p3, Q[3]);
        S[4] = pkadd(S[4], p4); Q[4] = pkfma(p4, p4, Q[4]);
        S[5] = pkadd(S[5], p5); Q[5] = pkfma(p5, p5, Q[5]);
        S[6] = pkadd(S[6], p6); Q[6] = pkfma(p6, p6, Q[6]);
        S[7] = pkadd(S[7], p7); Q[7] = pkfma(p7, p7, Q[7]);
    }
#pragma unroll
    for (int i = 0; i < 8; ++i) {
        S[i].x += __shfl_xor(S[i].x, 8); S[i].x += __shfl_xor(S[i].x, 16); S[i].x += __shfl_xor(S[i].x, 32);
        S[i].y += __shfl_xor(S[i].y, 8); S[i].y += __shfl_xor(S[i].y, 16); S[i].y += __shfl_xor(S[i].y, 32);
        Q[i].x += __shfl_xor(Q[i].x, 8); Q[i].x += __shfl_xor(Q[i].x, 16); Q[i].x += __shfl_xor(Q[i].x, 32);
        Q[i].y += __shfl_xor(Q[i].y, 8); Q[i].y += __shfl_xor(Q[i].y, 16); Q[i].y += __shfl_xor(Q[i].y, 32);
    }
    if (lane < 8) {                    // lane == c8; features 16*lane .. +15
#pragma unroll
        for (int i = 0; i < 8; ++i) {
            lds[wave][lane][2 * i]      = S[i].x;
            lds[wave][lane][2 * i + 1]  = S[i].y;
            lds[wave][lane][16 + 2 * i]     = Q[i].x;
            lds[wave][lane][16 + 2 * i + 1] = Q[i].y;
        }
    }
    __syncthreads();
    {
        const int kind = tid >> 7;         // 0 sums, 1 sumsq
        const int f = tid & 127;
        const int l = f >> 4, slot = (f & 15) + 16 * kind;
        float v = lds[0][l][slot] + lds[1][l][slot] + lds[2][l][slot] + lds[3][l][slot];
        partials[(size_t)blockIdx.x * 256 + tid] = v;
    }
    // last-block reduction (release: fence before ticket; acquire: fence after)
    __syncthreads();
    if (tid == 0) {
        __threadfence();
        unsigned int old = atomicAdd(done, 1u);
        isLast = (old == SB - 1) ? 1u : 0u;
    }
    __syncthreads();
    if (isLast) {
        __threadfence();
        float a0 = 0.f, a1 = 0.f, a2 = 0.f, a3 = 0.f;
        for (int bq = 0; bq < SB; bq += 4) {
            a0 += partials[(bq + 0) * 256 + tid];
            a1 += partials[(bq + 1) * 256 + tid];
            a2 += partials[(bq + 2) * 256 + tid];
            a3 += partials[(bq + 3) * 256 + tid];
        }
        stats[tid] = (a0 + a1) + (a2 + a3);
    }
}

// ---------------- fused norm + eicopy (fp8 agg in out1, 1:1 with ei copy) ----------------
__global__ __launch_bounds__(256) void k_normei(const unsigned int* __restrict__ agg8,
                                               const float* __restrict__ stats,
                                               const float* __restrict__ gw,
                                               const float* __restrict__ gb,
                                               const float* __restrict__ gms,
                                               float* __restrict__ out0,
                                               const int* __restrict__ ei,
                                               float* __restrict__ out1) {
    __shared__ float A[F], Bc[F];
    if (threadIdx.x < F) {
        int f = threadIdx.x;
        const float invn = 1.0f / (float)NN;
        float mean = stats[f] * invn;
        float ms = mean * gms[f];
        float var = stats[F + f] * invn - 2.0f * ms * mean + ms * ms;
        float inv = rsqrtf(var + EPS);
        float a = inv * gw[f];
        A[f] = a;
        Bc[f] = gb[f] - ms * a;
    }
    __syncthreads();
    const int c8 = threadIdx.x & 7;        // fixed uint4-column (features 16c8..16c8+15)
    float ra[16], rb[16];
#pragma unroll
    for (int i = 0; i < 16; ++i) { ra[i] = A[c8 * 16 + i]; rb[i] = Bc[c8 * 16 + i]; }
    const uint4* a4 = (const uint4*)agg8;
    const int4* ei4 = (const int4*)ei;
    float4* o14 = (float4*)out1;
    const long total  = (long)NN * 8;      // uint4 count == int4 count of ei
    const long stride = (long)gridDim.x * 256;
    for (long i = (long)blockIdx.x * 256 + threadIdx.x; i < total; i += stride) {
        uint4 v = a4[i];
        f32x2 p0 = fp8lo(v.x), p1 = fp8hi(v.x), p2 = fp8lo(v.y), p3 = fp8hi(v.y);
        f32x2 p4 = fp8lo(v.z), p5 = fp8hi(v.z), p6 = fp8lo(v.w), p7 = fp8hi(v.w);
        float fv[16];
        fv[0] = p0.x * ra[0] + rb[0];   fv[1] = p0.y * ra[1] + rb[1];
        fv[2] = p1.x * ra[2] + rb[2];   fv[3] = p1.y * ra[3] + rb[3];
        fv[4] = p2.x * ra[4] + rb[4];   fv[5] = p2.y * ra[5] + rb[5];
        fv[6] = p3.x * ra[6] + rb[6];   fv[7] = p3.y * ra[7] + rb[7];
        fv[8] = p4.x * ra[8] + rb[8];   fv[9] = p4.y * ra[9] + rb[9];
        fv[10] = p5.x * ra[10] + rb[10]; fv[11] = p5.y * ra[11] + rb[11];
        fv[12] = p6.x * ra[12] + rb[12]; fv[13] = p6.y * ra[13] + rb[13];
        fv[14] = p7.x * ra[14] + rb[14]; fv[15] = p7.y * ra[15] + rb[15];
#pragma unroll
        for (int t = 0; t < 16; ++t) fv[t] = fv[t] > 0.f ? fv[t] : SLOPE * fv[t];
        float* op = out0 + i * 16;
#pragma unroll
        for (int t = 0; t < 4; ++t) {
            float4 r; r.x = fv[4 * t]; r.y = fv[4 * t + 1]; r.z = fv[4 * t + 2]; r.w = fv[4 * t + 3];
            *(float4*)(op + 4 * t) = r;
        }
        // ei copy overwrites the same 16 bytes this thread just read from agg8
        int4 ev = ei4[i];
        unsigned int z;                       // opaque zero derived from v.x:
        asm("v_and_b32 %0, 0, %1" : "=v"(z) : "v"(v.x));
        float4 r;
        r.x = (float)(ev.x | (int)z);         // store depends on agg load
        r.y = (float)ev.y;
        r.z = (float)ev.z;
        r.w = (float)ev.w;
        o14[i] = r;
    }
}

extern "C" void kernel_launch(void* const* d_in, const int* in_sizes, int n_in,
                              void* d_out, int out_size, void* d_ws, size_t ws_size,
                              hipStream_t stream) {
    const float* x   = (const float*)d_in[0];
    const int*   ei  = (const int*)d_in[1];
    const float* Wm  = (const float*)d_in[2];
    const float* b   = (const float*)d_in[3];
    const float* gw  = (const float*)d_in[4];
    const float* gb  = (const float*)d_in[5];
    const float* gms = (const float*)d_in[6];

    float* out  = (float*)d_out;                 // region0: NN*F, region1: 2*NE
    float* out1 = out + (size_t)NN * F;
    unsigned int* agg8 = (unsigned int*)out1;    // NN*32 u32 = 2*NE u32, exact fit

    // ws layout (u32 units). ebuf aliases g32: ebuf consumed by k_fill2 before k_gemm writes g.
    unsigned int* wsu   = (unsigned int*)d_ws;
    unsigned int* g32   = wsu;                          // NN*32 u32 (12.8 MB, fp8 rows)
    unsigned int* ebuf  = wsu;                          // NE u32 (6.4 MB) — alias of g32
    unsigned int* mat   = g32 + (size_t)NN * 32;        // MATP (padded)
    unsigned int* scn   = mat + MATP;                   // MATP
    unsigned int* bsums = scn + MATP;                   // 128
    int* row_start      = (int*)(bsums + 128);          // NN+1
    int* csr            = row_start + NN + 2;           // NE (+8 pad)
    float* dis          = (float*)(csr + NE + 8);       // NN
    float* stats        = dis + NN;                     // 256
    unsigned int* Wt    = (unsigned int*)(stats + 256); // 8192
    unsigned int* done  = Wt + 8192;                    // 1 (+63 pad)
    float* partials     = (float*)(done + 64);          // SB*256 (256 KB)

    k_hist1<<<B1, 1024, 0, stream>>>(ei + NE, mat, Wm, Wt, done);
    k_scanA<<<98, 1024, 0, stream>>>(mat, scn, bsums);
    k_scat1<<<B1, 1024, 0, stream>>>(ei, mat, scn, bsums, ebuf);
    k_fill2<<<NBKT, 256, 0, stream>>>(mat, scn, bsums, ebuf, row_start, dis, csr);
    k_gemm<<<(NN + 127) / 128, 256, 0, stream>>>(x, Wt, dis, g32);
    k_gather<<<NN / 8, 512, 0, stream>>>(g32, csr, row_start, dis, b, agg8);
    k_stats<<<SB, 256, 0, stream>>>(agg8, partials, stats, done);
    k_normei<<<2048, 256, 0, stream>>>(agg8, stats, gw, gb, gms, out, ei, out1);
}

// Round 16
// 136.093 us; speedup vs baseline: 1.0545x; 1.0545x over previous
//
#include <hip/hip_runtime.h>

#define NN 100000
#define NE 1600000
#define F  128

// radix partition params
#define SH   8                  // bucket = dst >> 8
#define NPB  256                // nodes per bucket
#define NBKT 391                // ceil(NN/256)
#define B1   256                // pass-1 blocks
#define CH1  6250               // NE / B1 exactly
#define MATN (NBKT * B1)        // 100096
#define MATP (98 * 1024)        // padded to scan grid (100352)
#define BCAP2 6144              // fill2 LDS stage cap (mean 4096, +32 sigma)

#define SB   256                // stats blocks (partials, no atomics)

constexpr float EPS   = 1e-5f;
constexpr float SLOPE = 0.01f;

typedef __attribute__((ext_vector_type(8))) short short8;
typedef __attribute__((ext_vector_type(4))) float f32x4;
typedef __attribute__((ext_vector_type(2))) float f32x2;

__device__ inline unsigned int bf16rne(float f) {
    unsigned int u = __float_as_uint(f);
    return (u + 0x7fffu + ((u >> 16) & 1u)) >> 16;
}
__device__ inline unsigned int pack2(float a, float b) {
    return bf16rne(a) | (bf16rne(b) << 16);
}
__device__ inline f32x2 pkadd(f32x2 a, f32x2 b) {
    f32x2 d;
    asm("v_pk_add_f32 %0, %1, %2" : "=v"(d) : "v"(a), "v"(b));
    return d;
}
__device__ inline f32x2 pkfma(f32x2 a, f32x2 b, f32x2 c) {
    f32x2 d;
    asm("v_pk_fma_f32 %0, %1, %2, %3" : "=v"(d) : "v"(a), "v"(b), "v"(c));
    return d;
}
// fp8 e4m3 HW converters (gfx950 OCP fp8)
__device__ inline f32x2 fp8lo(unsigned int u) {
    return __builtin_amdgcn_cvt_pk_f32_fp8(u, false);   // bytes 0,1 -> 2 floats
}
__device__ inline f32x2 fp8hi(unsigned int u) {
    return __builtin_amdgcn_cvt_pk_f32_fp8(u, true);    // bytes 2,3 -> 2 floats
}
__device__ inline unsigned int fp8pack4(float a, float b, float c, float d) {
    int o = 0;
    o = __builtin_amdgcn_cvt_pk_fp8_f32(a, b, o, false);
    o = __builtin_amdgcn_cvt_pk_fp8_f32(c, d, o, true);
    return (unsigned int)o;
}

// ---------------- pass 1a: per-block bucket histogram + (blocks 0-7) W prep ----------------
__global__ __launch_bounds__(1024) void k_hist1(const int* __restrict__ dst,
                                                unsigned int* __restrict__ mat,
                                                const float* __restrict__ Wm,
                                                unsigned int* __restrict__ Wt) {
    __shared__ unsigned int h[NBKT];
    if (threadIdx.x < NBKT) h[threadIdx.x] = 0u;
    __syncthreads();
    if (blockIdx.x < 8) {                        // fused W prep (8192 entries)
        int idx = blockIdx.x * 1024 + threadIdx.x;
        int p = idx & 3, lane = (idx >> 2) & 63, n = (idx >> 8) & 7, kk = idx >> 11;
        int k0 = kk * 32 + (lane >> 4) * 8 + 2 * p;
        int c  = n * 16 + (lane & 15);
        unsigned int lo = bf16rne(Wm[k0 * F + c]);
        unsigned int hi = bf16rne(Wm[(k0 + 1) * F + c]);
        Wt[idx] = lo | (hi << 16);
    }
    const int e0 = blockIdx.x * CH1;
    for (int i = threadIdx.x; i < CH1; i += 1024)
        atomicAdd(&h[dst[e0 + i] >> SH], 1u);
    __syncthreads();
    if (threadIdx.x < NBKT) mat[threadIdx.x * B1 + blockIdx.x] = h[threadIdx.x];
}

// ---------------- scanA: inclusive per 1024-block + block sums ----------------
__global__ __launch_bounds__(1024) void k_scanA(const unsigned int* __restrict__ mat,
                                                unsigned int* __restrict__ scn,
                                                unsigned int* __restrict__ bsums) {
    __shared__ unsigned int ps[1024];
    const int t = threadIdx.x;
    const int i = blockIdx.x * 1024 + t;        // grid 98*1024 == MATP
    unsigned int v = mat[i];                     // pad region: garbage, harmless
    ps[t] = v;
    __syncthreads();
    for (int off = 1; off < 1024; off <<= 1) {
        unsigned int a = (t >= off) ? ps[t - off] : 0u;
        __syncthreads();
        ps[t] += a;
        __syncthreads();
    }
    scn[i] = ps[t];                              // inclusive within block
    if (t == 1023) bsums[blockIdx.x] = ps[1023];
}

// exclusive(i) = scn[i] + boff[i>>10] - mat[i]; boff computed in-block from bsums

// ---------------- pass 1c: scatter edges into bucket segments ----------------
__global__ __launch_bounds__(1024) void k_scat1(const int* __restrict__ ei,
                                                const unsigned int* __restrict__ mat,
                                                const unsigned int* __restrict__ scn,
                                                const unsigned int* __restrict__ bsums,
                                                unsigned int* __restrict__ ebuf) {
    __shared__ unsigned int cur[NBKT];
    __shared__ unsigned int bo[128];
    const int t = threadIdx.x;
    if (t < 128) {                               // 98-entry exclusive scan of bsums
        unsigned int v = (t < 98) ? bsums[t] : 0u;
        bo[t] = v;
        for (int off = 1; off < 128; off <<= 1) {
            __syncthreads();
            unsigned int a = (t >= off) ? bo[t - off] : 0u;
            __syncthreads();
            bo[t] += a;
        }
        bo[t] -= v;                              // exclusive
    } else {
        for (int off = 1; off < 128; off <<= 1) { __syncthreads(); __syncthreads(); }
    }
    __syncthreads();
    if (t < NBKT) {
        int idx = t * B1 + blockIdx.x;
        cur[t] = scn[idx] + bo[idx >> 10] - mat[idx];
    }
    __syncthreads();
    const int e0 = blockIdx.x * CH1;
    for (int i = t; i < CH1; i += 1024) {
        int s = ei[e0 + i];
        int d = ei[NE + e0 + i];
        unsigned int pos = atomicAdd(&cur[d >> SH], 1u);
        ebuf[pos] = ((unsigned int)(d & (NPB - 1)) << 17) | (unsigned int)s;
    }
}

// ---------------- pass 2: LDS-staged per-bucket degree/scan/row_start/dis + csr ----------------
__global__ __launch_bounds__(256) void k_fill2(const unsigned int* __restrict__ mat,
                                               const unsigned int* __restrict__ scn,
                                               const unsigned int* __restrict__ bsums,
                                               const unsigned int* __restrict__ ebuf,
                                               int* __restrict__ row_start,
                                               float* __restrict__ dis,
                                               int* __restrict__ csr) {
    __shared__ unsigned int stage[BCAP2];
    __shared__ unsigned int hist[NPB];
    __shared__ unsigned int cur[NPB];
    __shared__ unsigned int ps[NPB];
    __shared__ unsigned int bo[128];
    const int t = threadIdx.x;
    const int bkt = blockIdx.x;
    hist[t] = 0u;
    if (t < 128) {                               // 98-entry exclusive scan of bsums
        unsigned int v = (t < 98) ? bsums[t] : 0u;
        bo[t] = v;
        for (int off = 1; off < 128; off <<= 1) {
            __syncthreads();
            unsigned int a = (t >= off) ? bo[t - off] : 0u;
            __syncthreads();
            bo[t] += a;
        }
        bo[t] -= v;
    } else {
        for (int off = 1; off < 128; off <<= 1) { __syncthreads(); __syncthreads(); }
    }
    __syncthreads();
    const int i0 = bkt * B1;
    const unsigned int ebase = scn[i0] + bo[i0 >> 10] - mat[i0];
    unsigned int eend;
    if (bkt == NBKT - 1) eend = (unsigned int)NE;
    else {
        const int i1 = (bkt + 1) * B1;
        eend = scn[i1] + bo[i1 >> 10] - mat[i1];
    }
    const unsigned int n = eend - ebase;
    const unsigned int m = (n < BCAP2) ? n : BCAP2;
    for (unsigned int i = t; i < m; i += 256) {
        unsigned int v = ebuf[ebase + i];
        stage[i] = v;
        atomicAdd(&hist[v >> 17], 1u);
    }
    for (unsigned int i = BCAP2 + t; i < n; i += 256)   // overflow path (≈never)
        atomicAdd(&hist[ebuf[ebase + i] >> 17], 1u);
    __syncthreads();
    const unsigned int deg = hist[t];
    ps[t] = deg;
    __syncthreads();
    for (int off = 1; off < 256; off <<= 1) {
        unsigned int a = (t >= off) ? ps[t - off] : 0u;
        __syncthreads();
        ps[t] += a;
        __syncthreads();
    }
    const unsigned int ex = (t == 0) ? 0u : ps[t - 1];
    cur[t] = ebase + ex;
    const int node = bkt * NPB + t;
    if (node <= NN) row_start[node] = (int)(ebase + ex);   // node==NN lands on NE
    if (node < NN)  dis[node] = rsqrtf((float)(deg + 1u));
    __syncthreads();
    for (unsigned int i = t; i < m; i += 256) {
        unsigned int v = stage[i];
        unsigned int pos = atomicAdd(&cur[v >> 17], 1u);
        csr[pos] = (int)(v & 0x1FFFFu);
    }
    for (unsigned int i = BCAP2 + t; i < n; i += 256) {   // overflow path
        unsigned int v = ebuf[ebase + i];
        unsigned int pos = atomicAdd(&cur[v >> 17], 1u);
        csr[pos] = (int)(v & 0x1FFFFu);
    }
}

// ---------------- MFMA GEMM: g = fp8(x @ W * dis)  (swapped operands) ----------------
__global__ __launch_bounds__(256) void k_gemm(const float* __restrict__ x,
                                              const unsigned int* __restrict__ Wt,
                                              const float* __restrict__ dis,
                                              unsigned int* __restrict__ g32) {
    __shared__ unsigned int xl[128 * 64];   // 32 KB bf16-pair tile
    const int tid = threadIdx.x;
    const int lane = tid & 63, wave = tid >> 6;
    const int row0 = blockIdx.x * 128;

#pragma unroll
    for (int i = 0; i < 16; ++i) {
        int fi = i * 256 + tid;            // 0..4095
        int lr = fi >> 5;                  // local row (32 thr/row)
        int cf = (fi & 31) * 4;            // f32 col
        int gr = row0 + lr; if (gr >= NN) gr = NN - 1;
        float4 v = *(const float4*)(x + (size_t)gr * F + cf);
        unsigned int u0 = pack2(v.x, v.y);
        unsigned int u1 = pack2(v.z, v.w);
        int cu = (cf >> 1) ^ ((lr & 7) << 2);
        uint2 w2; w2.x = u0; w2.y = u1;
        *(uint2*)&xl[lr * 64 + cu] = w2;
    }
    __syncthreads();

    const int rbase = row0 + wave * 32;
    short8 afr[2][4];                       // x fragments (B operand)
#pragma unroll
    for (int m = 0; m < 2; ++m) {
        int lr = wave * 32 + m * 16 + (lane & 15);
#pragma unroll
        for (int kk = 0; kk < 4; ++kk) {
            int cu = (kk * 16 + (lane >> 4) * 4) ^ ((lr & 7) << 2);
            afr[m][kk] = *(const short8*)&xl[lr * 64 + cu];
        }
    }

    f32x4 acc[2][8];
#pragma unroll
    for (int m = 0; m < 2; ++m)
#pragma unroll
        for (int n = 0; n < 8; ++n) { f32x4 z = {0.f, 0.f, 0.f, 0.f}; acc[m][n] = z; }

    const uint4* Wt4 = (const uint4*)Wt;
#pragma unroll
    for (int kk = 0; kk < 4; ++kk) {
        union { uint4 u; short8 s; } bfr[8];   // W^T fragments (A operand)
#pragma unroll
        for (int n = 0; n < 8; ++n) bfr[n].u = Wt4[(kk * 8 + n) * 64 + lane];
#pragma unroll
        for (int m = 0; m < 2; ++m)
#pragma unroll
            for (int n = 0; n < 8; ++n)
                acc[m][n] = __builtin_amdgcn_mfma_f32_16x16x32_bf16(bfr[n].s, afr[m][kk], acc[m][n], 0, 0, 0);
    }

    // epilogue: lane owns xrow = rbase + m*16 + (lane&15), wcols n*16+(lane>>4)*4 .. +3
#pragma unroll
    for (int m = 0; m < 2; ++m) {
        int xr = rbase + m * 16 + (lane & 15);
        bool ok = xr < NN;
        float d = ok ? dis[xr] : 0.0f;
        unsigned int* gp = g32 + (size_t)(ok ? xr : 0) * 32 + (lane >> 4);
#pragma unroll
        for (int n = 0; n < 8; ++n) {
            unsigned int w = fp8pack4(acc[m][n][0] * d, acc[m][n][1] * d,
                                      acc[m][n][2] * d, acc[m][n][3] * d);
            if (ok) gp[n * 4] = w;
        }
    }
}

// ---------------- gather: agg8 = fp8(b + dis[n]*sum(g[src] over src ∪ {n})) ----------------
// wave per node; fp8 rows (128B = 2 lines); 16 lanes/row (uint2), 4 row-slots,
// 4 rows unrolled per iter; HW fp8 cvt + v_pk_add_f32; 2-stage shfl reduce; fp8 out.
__global__ __launch_bounds__(256) void k_gather(const unsigned int* __restrict__ g32,
                                                const int* __restrict__ csr,
                                                const int* __restrict__ row_start,
                                                const float* __restrict__ dis,
                                                const float* __restrict__ b,
                                                unsigned int* __restrict__ agg8) {
    const int lane = threadIdx.x & 63;
    const int node = blockIdx.x * 4 + (threadIdx.x >> 6);
    if (node >= NN) return;
    const int q = lane >> 4;           // row slot (0..3)
    const int c = lane & 15;           // uint2 col: features 8c..8c+7
    const int j = row_start[node];
    const int e = row_start[node + 1];
    const int L = e - j + 1;           // + self
    int sv = (j + lane < e) ? csr[j + lane] : node;   // preload ids; self past end
    f32x2 A0 = {0.f, 0.f}, A1 = A0, A2 = A0, A3 = A0;
    int k = 0;
    const int L1 = (L < 64) ? L : 64;
    for (; k < L1; k += 16) {
        int k0 = k + q, k1 = k0 + 4, k2 = k0 + 8, k3 = k0 + 12;
        int r0 = __shfl(sv, k0);
        int r1 = __shfl(sv, k1);
        int r2 = __shfl(sv, k2);
        int r3 = __shfl(sv, k3);
        bool p0 = k0 < L, p1 = k1 < L, p2 = k2 < L, p3 = k3 < L;
        uint2 v0, v1, v2, v3;
        if (p0) v0 = *(const uint2*)&g32[(size_t)r0 * 32 + c * 2];
        if (p1) v1 = *(const uint2*)&g32[(size_t)r1 * 32 + c * 2];
        if (p2) v2 = *(const uint2*)&g32[(size_t)r2 * 32 + c * 2];
        if (p3) v3 = *(const uint2*)&g32[(size_t)r3 * 32 + c * 2];
        if (p0) {
            A0 = pkadd(A0, fp8lo(v0.x)); A1 = pkadd(A1, fp8hi(v0.x));
            A2 = pkadd(A2, fp8lo(v0.y)); A3 = pkadd(A3, fp8hi(v0.y));
        }
        if (p1) {
            A0 = pkadd(A0, fp8lo(v1.x)); A1 = pkadd(A1, fp8hi(v1.x));
            A2 = pkadd(A2, fp8lo(v1.y)); A3 = pkadd(A3, fp8hi(v1.y));
        }
        if (p2) {
            A0 = pkadd(A0, fp8lo(v2.x)); A1 = pkadd(A1, fp8hi(v2.x));
            A2 = pkadd(A2, fp8lo(v2.y)); A3 = pkadd(A3, fp8hi(v2.y));
        }
        if (p3) {
            A0 = pkadd(A0, fp8lo(v3.x)); A1 = pkadd(A1, fp8hi(v3.x));
            A2 = pkadd(A2, fp8lo(v3.y)); A3 = pkadd(A3, fp8hi(v3.y));
        }
    }
    for (; k < L; k += 16) {           // rare: deg+1 > 64
#pragma unroll
        for (int s = 0; s < 4; ++s) {
            int ks = k + q + s * 4;
            if (ks < L) {
                int rs = (j + ks < e) ? csr[j + ks] : node;
                uint2 v = *(const uint2*)&g32[(size_t)rs * 32 + c * 2];
                A0 = pkadd(A0, fp8lo(v.x)); A1 = pkadd(A1, fp8hi(v.x));
                A2 = pkadd(A2, fp8lo(v.y)); A3 = pkadd(A3, fp8hi(v.y));
            }
        }
    }
#define RED2(A) A.x += __shfl_xor(A.x, 16); A.x += __shfl_xor(A.x, 32); \
                A.y += __shfl_xor(A.y, 16); A.y += __shfl_xor(A.y, 32);
    RED2(A0) RED2(A1) RED2(A2) RED2(A3)
#undef RED2
    if (q == 0) {                      // lanes 0..15 write the row (128B contiguous)
        float d = dis[node];
        const float4* bp = (const float4*)&b[c * 8];
        float4 b0 = bp[0], b1 = bp[1];
        uint2 w;
        w.x = fp8pack4(b0.x + d * A0.x, b0.y + d * A0.y,
                       b0.z + d * A1.x, b0.w + d * A1.y);
        w.y = fp8pack4(b1.x + d * A2.x, b1.y + d * A2.y,
                       b1.z + d * A3.x, b1.w + d * A3.y);
        *(uint2*)&agg8[(size_t)node * 32 + c * 2] = w;
    }
}

// ---------------- stats: fp8 agg uint4 streaming, pk_fma, shfl+LDS reduce ----------------
// stride % 8 == 0 -> thread owns fixed uint4-column c8 (features 16c8..16c8+15).
__global__ __launch_bounds__(256) void k_stats(const unsigned int* __restrict__ agg8,
                                               float* __restrict__ partials) {
    __shared__ float lds[4][8][32];
    const int tid = threadIdx.x;
    const int lane = tid & 63, wave = tid >> 6;
    const uint4* a4 = (const uint4*)agg8;
    const long total  = (long)NN * 8;
    const long stride = (long)SB * 256;
    f32x2 S[8], Q[8];
#pragma unroll
    for (int i = 0; i < 8; ++i) { f32x2 z = {0.f, 0.f}; S[i] = z; Q[i] = z; }
    for (long i = (long)blockIdx.x * 256 + tid; i < total; i += stride) {
        uint4 v = a4[i];
        f32x2 p0 = fp8lo(v.x), p1 = fp8hi(v.x), p2 = fp8lo(v.y), p3 = fp8hi(v.y);
        f32x2 p4 = fp8lo(v.z), p5 = fp8hi(v.z), p6 = fp8lo(v.w), p7 = fp8hi(v.w);
        S[0] = pkadd(S[0], p0); Q[0] = pkfma(p0, p0, Q[0]);
        S[1] = pkadd(S[1], p1); Q[1] = pkfma(p1, p1, Q[1]);
        S[2] = pkadd(S[2], p2); Q[2] = pkfma(p2, p2, Q[2]);
        S[3] = pkadd(S[3], p3); Q[3] = pkfma(p3, p3, Q[3]);
        S[4] = pkadd(S[4], p4); Q[4] = pkfma(p4, p4, Q[4]);
        S[5] = pkadd(S[5], p5); Q[5] = pkfma(p5, p5, Q[5]);
        S[6] = pkadd(S[6], p6); Q[6] = pkfma(p6, p6, Q[6]);
        S[7] = pkadd(S[7], p7); Q[7] = pkfma(p7, p7, Q[7]);
    }
#pragma unroll
    for (int i = 0; i < 8; ++i) {
        S[i].x += __shfl_xor(S[i].x, 8); S[i].x += __shfl_xor(S[i].x, 16); S[i].x += __shfl_xor(S[i].x, 32);
        S[i].y += __shfl_xor(S[i].y, 8); S[i].y += __shfl_xor(S[i].y, 16); S[i].y += __shfl_xor(S[i].y, 32);
        Q[i].x += __shfl_xor(Q[i].x, 8); Q[i].x += __shfl_xor(Q[i].x, 16); Q[i].x += __shfl_xor(Q[i].x, 32);
        Q[i].y += __shfl_xor(Q[i].y, 8); Q[i].y += __shfl_xor(Q[i].y, 16); Q[i].y += __shfl_xor(Q[i].y, 32);
    }
    if (lane < 8) {                    // lane == c8; features 16*lane .. +15
#pragma unroll
        for (int i = 0; i < 8; ++i) {
            lds[wave][lane][2 * i]      = S[i].x;
            lds[wave][lane][2 * i + 1]  = S[i].y;
            lds[wave][lane][16 + 2 * i]     = Q[i].x;
            lds[wave][lane][16 + 2 * i + 1] = Q[i].y;
        }
    }
    __syncthreads();
    const int kind = tid >> 7;         // 0 sums, 1 sumsq
    const int f = tid & 127;
    const int l = f >> 4, slot = (f & 15) + 16 * kind;
    float v = lds[0][l][slot] + lds[1][l][slot] + lds[2][l][slot] + lds[3][l][slot];
    partials[(size_t)blockIdx.x * 256 + tid] = v;
}

// ---------------- reduce partials -> stats[256] (sums | sumsq) ----------------
__global__ __launch_bounds__(256) void k_red(const float* __restrict__ partials,
                                             float* __restrict__ stats) {
    float a0 = 0.f, a1 = 0.f, a2 = 0.f, a3 = 0.f;
    for (int bq = 0; bq < SB; bq += 4) {
        a0 += partials[(bq + 0) * 256 + threadIdx.x];
        a1 += partials[(bq + 1) * 256 + threadIdx.x];
        a2 += partials[(bq + 2) * 256 + threadIdx.x];
        a3 += partials[(bq + 3) * 256 + threadIdx.x];
    }
    stats[threadIdx.x] = (a0 + a1) + (a2 + a3);
}

// ---------------- fused norm + eicopy (fp8 agg in out1, 1:1 with ei copy) ----------------
__global__ __launch_bounds__(256) void k_normei(const unsigned int* __restrict__ agg8,
                                               const float* __restrict__ stats,
                                               const float* __restrict__ gw,
                                               const float* __restrict__ gb,
                                               const float* __restrict__ gms,
                                               float* __restrict__ out0,
                                               const int* __restrict__ ei,
                                               float* __restrict__ out1) {
    __shared__ float A[F], Bc[F];
    if (threadIdx.x < F) {
        int f = threadIdx.x;
        const float invn = 1.0f / (float)NN;
        float mean = stats[f] * invn;
        float ms = mean * gms[f];
        float var = stats[F + f] * invn - 2.0f * ms * mean + ms * ms;
        float inv = rsqrtf(var + EPS);
        float a = inv * gw[f];
        A[f] = a;
        Bc[f] = gb[f] - ms * a;
    }
    __syncthreads();
    const int c8 = threadIdx.x & 7;        // fixed uint4-column (features 16c8..16c8+15)
    float ra[16], rb[16];
#pragma unroll
    for (int i = 0; i < 16; ++i) { ra[i] = A[c8 * 16 + i]; rb[i] = Bc[c8 * 16 + i]; }
    const uint4* a4 = (const uint4*)agg8;
    const int4* ei4 = (const int4*)ei;
    float4* o14 = (float4*)out1;
    const long total  = (long)NN * 8;      // uint4 count == int4 count of ei
    const long stride = (long)gridDim.x * 256;
    for (long i = (long)blockIdx.x * 256 + threadIdx.x; i < total; i += stride) {
        uint4 v = a4[i];
        f32x2 p0 = fp8lo(v.x), p1 = fp8hi(v.x), p2 = fp8lo(v.y), p3 = fp8hi(v.y);
        f32x2 p4 = fp8lo(v.z), p5 = fp8hi(v.z), p6 = fp8lo(v.w), p7 = fp8hi(v.w);
        float fv[16];
        fv[0] = p0.x * ra[0] + rb[0];   fv[1] = p0.y * ra[1] + rb[1];
        fv[2] = p1.x * ra[2] + rb[2];   fv[3] = p1.y * ra[3] + rb[3];
        fv[4] = p2.x * ra[4] + rb[4];   fv[5] = p2.y * ra[5] + rb[5];
        fv[6] = p3.x * ra[6] + rb[6];   fv[7] = p3.y * ra[7] + rb[7];
        fv[8] = p4.x * ra[8] + rb[8];   fv[9] = p4.y * ra[9] + rb[9];
        fv[10] = p5.x * ra[10] + rb[10]; fv[11] = p5.y * ra[11] + rb[11];
        fv[12] = p6.x * ra[12] + rb[12]; fv[13] = p6.y * ra[13] + rb[13];
        fv[14] = p7.x * ra[14] + rb[14]; fv[15] = p7.y * ra[15] + rb[15];
#pragma unroll
        for (int t = 0; t < 16; ++t) fv[t] = fv[t] > 0.f ? fv[t] : SLOPE * fv[t];
        float* op = out0 + i * 16;
#pragma unroll
        for (int t = 0; t < 4; ++t) {
            float4 r; r.x = fv[4 * t]; r.y = fv[4 * t + 1]; r.z = fv[4 * t + 2]; r.w = fv[4 * t + 3];
            *(float4*)(op + 4 * t) = r;
        }
        // ei copy overwrites the same 16 bytes this thread just read from agg8
        int4 ev = ei4[i];
        unsigned int z;                       // opaque zero derived from v.x:
        asm("v_and_b32 %0, 0, %1" : "=v"(z) : "v"(v.x));
        float4 r;
        r.x = (float)(ev.x | (int)z);         // store depends on agg load
        r.y = (float)ev.y;
        r.z = (float)ev.z;
        r.w = (float)ev.w;
        o14[i] = r;
    }
}

extern "C" void kernel_launch(void* const* d_in, const int* in_sizes, int n_in,
                              void* d_out, int out_size, void* d_ws, size_t ws_size,
                              hipStream_t stream) {
    const float* x   = (const float*)d_in[0];
    const int*   ei  = (const int*)d_in[1];
    const float* Wm  = (const float*)d_in[2];
    const float* b   = (const float*)d_in[3];
    const float* gw  = (const float*)d_in[4];
    const float* gb  = (const float*)d_in[5];
    const float* gms = (const float*)d_in[6];

    float* out  = (float*)d_out;                 // region0: NN*F, region1: 2*NE
    float* out1 = out + (size_t)NN * F;
    unsigned int* agg8 = (unsigned int*)out1;    // NN*32 u32 = 2*NE u32, exact fit

    // ws layout (u32 units). ebuf aliases g32: ebuf consumed by k_fill2 before k_gemm writes g.
    unsigned int* wsu   = (unsigned int*)d_ws;
    unsigned int* g32   = wsu;                          // NN*32 u32 (12.8 MB, fp8 rows)
    unsigned int* ebuf  = wsu;                          // NE u32 (6.4 MB) — alias of g32
    unsigned int* mat   = g32 + (size_t)NN * 32;        // MATP (padded)
    unsigned int* scn   = mat + MATP;                   // MATP
    unsigned int* bsums = scn + MATP;                   // 128
    int* row_start      = (int*)(bsums + 128);          // NN+1
    int* csr            = row_start + NN + 2;           // NE (+8 pad)
    float* dis          = (float*)(csr + NE + 8);       // NN
    float* stats        = dis + NN;                     // 256
    unsigned int* Wt    = (unsigned int*)(stats + 256); // 8192
    float* partials     = (float*)(Wt + 8192);          // SB*256 (256 KB)

    k_hist1<<<B1, 1024, 0, stream>>>(ei + NE, mat, Wm, Wt);
    k_scanA<<<98, 1024, 0, stream>>>(mat, scn, bsums);
    k_scat1<<<B1, 1024, 0, stream>>>(ei, mat, scn, bsums, ebuf);
    k_fill2<<<NBKT, 256, 0, stream>>>(mat, scn, bsums, ebuf, row_start, dis, csr);
    k_gemm<<<(NN + 127) / 128, 256, 0, stream>>>(x, Wt, dis, g32);
    k_gather<<<NN / 4, 256, 0, stream>>>(g32, csr, row_start, dis, b, agg8);
    k_stats<<<SB, 256, 0, stream>>>(agg8, partials);
    k_red<<<1, 256, 0, stream>>>(partials, stats);
    k_normei<<<2048, 256, 0, stream>>>(agg8, stats, gw, gb, gms, out, ei, out1);
}